// Round 8
// baseline (2765.099 us; speedup 1.0000x reference)
//
#include <hip/hip_runtime.h>

typedef __attribute__((ext_vector_type(8))) short short8;
typedef __attribute__((ext_vector_type(4))) float f32x4;
typedef unsigned int uint;
typedef unsigned short ushort;

#define T_ 256
#define B_ 16
#define D_ 256
#define H_ 512
#define V_ 32000
#define GH 2048   /* 4*H */
#define SENT 0xFFFFFFFFu

__device__ __forceinline__ ushort f2bf(float f) {
    uint u = __float_as_uint(f);
    u += 0x7FFFu + ((u >> 16) & 1u);
    return (ushort)(u >> 16);
}

__device__ __forceinline__ float fsig(float x) {
    return 1.0f / (1.0f + __expf(-x));
}

__device__ __forceinline__ float ftanh(float x) {
    float a = __expf(-2.0f * fabsf(x));
    float t = (1.0f - a) / (1.0f + a);
    return x >= 0.0f ? t : -t;
}

__device__ __forceinline__ void cvt4(const float* s, ushort* d) {
    float4 v = *(const float4*)s;
    ushort4 o;
    o.x = f2bf(v.x); o.y = f2bf(v.y); o.z = f2bf(v.z); o.w = f2bf(v.w);
    *(ushort4*)d = o;
}

__device__ __forceinline__ uint aload(const uint* p) {
    return __hip_atomic_load(p, __ATOMIC_RELAXED, __HIP_MEMORY_SCOPE_AGENT);
}

// ---------------------------------------------------------------- prep ----
__global__ void prep_convert(const float* __restrict__ Wih, const float* __restrict__ Whh,
                             const float* __restrict__ Wfc, const float* __restrict__ bih,
                             const float* __restrict__ bhh,
                             ushort* __restrict__ dWih, ushort* __restrict__ dWhh,
                             ushort* __restrict__ dWfc, float* __restrict__ bsum) {
    const long nA = (long)GH * D_ / 4;
    const long nB = (long)GH * H_ / 4;
    const long nC = (long)V_ * H_ / 4;
    const long nS = GH / 4;
    long i = (long)blockIdx.x * blockDim.x + threadIdx.x;
    if (i >= nA + nB + nC + nS) return;
    if (i < nA) {
        cvt4(Wih + i * 4, dWih + i * 4);
    } else if (i < nA + nB) {
        long j = i - nA;
        cvt4(Whh + j * 4, dWhh + j * 4);
    } else if (i < nA + nB + nC) {
        long j = i - nA - nB;
        cvt4(Wfc + j * 4, dWfc + j * 4);
    } else {
        long j = (i - nA - nB - nC) * 4;
        float4 a = *(const float4*)(bih + j);
        float4 b = *(const float4*)(bhh + j);
        float4 o;
        o.x = a.x + b.x; o.y = a.y + b.y; o.z = a.z + b.z; o.w = a.w + b.w;
        *(float4*)(bsum + j) = o;
    }
}

__global__ void prep_xseq(const float* __restrict__ images, const int* __restrict__ labels,
                          const float* __restrict__ embed, ushort* __restrict__ xseq) {
    int m = blockIdx.x;
    int l = threadIdx.x;
    int t = m >> 4, b = m & 15;
    const float* src = (t == 0) ? (images + b * D_) : (embed + (long)labels[m] * D_);
    cvt4(src + l * 4, xseq + (long)m * D_ + l * 4);
}

// ------------------------------------------------- 128x128 bf16 GEMM ------
// C(M x N) = A(M x K) * B(N x K)^T + bias[n];  A,B bf16 K-major, C f32.
template <int K>
__global__ __launch_bounds__(256) void gemm_bt(const ushort* __restrict__ A,
                                               const ushort* __restrict__ Bw,
                                               float* __restrict__ C,
                                               const float* __restrict__ bias,
                                               int ldc) {
    __shared__ ushort As[128 * 64];
    __shared__ ushort Bs[128 * 64];
    const int tid = threadIdx.x;
    const int lane = tid & 63;
    const int w = tid >> 6;
    const int wr = w >> 1, wc = w & 1;
    const long mBase = (long)blockIdx.x * 128;
    const long nBase = (long)blockIdx.y * 128;

    f32x4 acc[4][4];
#pragma unroll
    for (int i = 0; i < 4; ++i)
#pragma unroll
        for (int j = 0; j < 4; ++j) acc[i][j] = (f32x4){0.f, 0.f, 0.f, 0.f};

    const char* Ab = (const char*)A;
    const char* Bb = (const char*)Bw;

    for (int kk = 0; kk < K / 64; ++kk) {
#pragma unroll
        for (int it = 0; it < 4; ++it) {
            int c = w * 4 + it;
            int r = c * 8 + (lane >> 3);
            int sg = (lane & 7) ^ (r & 7);
            long aoff = (mBase + r) * (long)(K * 2) + kk * 128 + sg * 16;
            long boff = (nBase + r) * (long)(K * 2) + kk * 128 + sg * 16;
            __builtin_amdgcn_global_load_lds(
                (const __attribute__((address_space(1))) void*)(Ab + aoff),
                (__attribute__((address_space(3))) void*)((char*)As + c * 1024), 16, 0, 0);
            __builtin_amdgcn_global_load_lds(
                (const __attribute__((address_space(1))) void*)(Bb + boff),
                (__attribute__((address_space(3))) void*)((char*)Bs + c * 1024), 16, 0, 0);
        }
        __syncthreads();
#pragma unroll
        for (int k2 = 0; k2 < 2; ++k2) {
            short8 af[4], bfr[4];
#pragma unroll
            for (int mi = 0; mi < 4; ++mi) {
                int mrow = wr * 64 + mi * 16 + (lane & 15);
                int g = (k2 * 4 + (lane >> 4)) ^ (mrow & 7);
                af[mi] = *(const short8*)((const char*)As + mrow * 128 + g * 16);
            }
#pragma unroll
            for (int ni = 0; ni < 4; ++ni) {
                int nrow = wc * 64 + ni * 16 + (lane & 15);
                int g = (k2 * 4 + (lane >> 4)) ^ (nrow & 7);
                bfr[ni] = *(const short8*)((const char*)Bs + nrow * 128 + g * 16);
            }
#pragma unroll
            for (int mi = 0; mi < 4; ++mi)
#pragma unroll
                for (int ni = 0; ni < 4; ++ni)
                    acc[mi][ni] = __builtin_amdgcn_mfma_f32_16x16x32_bf16(
                        af[mi], bfr[ni], acc[mi][ni], 0, 0, 0);
        }
        __syncthreads();
    }
#pragma unroll
    for (int ni = 0; ni < 4; ++ni) {
        long col = nBase + wc * 64 + ni * 16 + (lane & 15);
        float bv = bias[col];
#pragma unroll
        for (int mi = 0; mi < 4; ++mi) {
            long row0 = mBase + wr * 64 + mi * 16 + ((lane >> 4) << 2);
#pragma unroll
            for (int rr = 0; rr < 4; ++rr)
                C[(row0 + rr) * (long)ldc + col] = acc[mi][ni][rr] + bv;
        }
    }
}

// ------------------------------------------------------------- scan ------
// 32 blocks x 256 threads; block g owns h columns [g*16, g*16+16).
// Sentinel protocol, register-direct A-path: each lane issues all 16 MFMA
// A-granule loads (relaxed agent-scope, pipelined) straight from hs; per-j
// wave-vote retry on sentinels, then MFMA from registers. No LDS h-staging,
// no pre-matvec barrier — the MALL wait overlaps the matvec. Single barrier
// per step (gb gate exchange). gb WAR across steps is closed by a real data
// dependency: wave w's j granules require ALL own-block publishes at t, and
// each publish's payload depends (via the shfl pack) on that row's gb reads.
__global__ __launch_bounds__(256) void lstm_scan(const ushort* __restrict__ Whh,
                                                 const float* __restrict__ xg,
                                                 ushort* __restrict__ hs) {
    __shared__ ushort Ws[64 * 512];   // 64 KB, swizzled granules
    __shared__ float gb[4][16][16];   // 4 KB

    const int tid = threadIdx.x;
    const int lane = tid & 63;
    const int w = tid >> 6;
    const int g = blockIdx.x;

    // Ws row r=q*16+jj  <->  W_hh row q*512 + g*16 + jj (q = gate)
#pragma unroll
    for (int j = 0; j < 16; ++j) {
        int gid = j * 256 + tid;
        int row = gid >> 6;
        int gcol = gid & 63;
        int srow = (row >> 4) * H_ + g * 16 + (row & 15);
        uint4 v = *(const uint4*)(Whh + (long)srow * H_ + gcol * 8);
        int dg = gcol ^ (row & 7);
        *(uint4*)((char*)Ws + row * 1024 + dg * 16) = v;
    }
    __syncthreads();

    const int b = tid >> 4;          // cell identity
    const int jj = tid & 15;
    const int arow = lane & 15;      // MFMA A row (batch)
    const int q = lane >> 4;         // MFMA k-quarter
    const int brow = w * 16 + (lane & 15);
    float cst = 0.0f;

    for (int t = 0; t < T_; ++t) {
        long xb = ((long)t * B_ + b) * GH + g * 16 + jj;
        float gi = xg[xb];
        float gf = xg[xb + 512];
        float gg = xg[xb + 1024];
        float go = xg[xb + 1536];

        if (t > 0) {
            // lane's A-granule stream: row arow, granule 4j+q  (16B each)
            const uint* hsrc = (const uint*)hs + (long)(t - 1) * (B_ * H_ / 2)
                               + arow * (H_ / 2) + q * 4;
            uint a[16][4];
#pragma unroll
            for (int j = 0; j < 16; ++j) {
#pragma unroll
                for (int d = 0; d < 4; ++d)
                    a[j][d] = aload(hsrc + j * 16 + d);
            }
            f32x4 acc0 = (f32x4){0.f, 0.f, 0.f, 0.f};
            f32x4 acc1 = (f32x4){0.f, 0.f, 0.f, 0.f};
#pragma unroll
            for (int j = 0; j < 16; ++j) {
                int miss = (a[j][0] == SENT) | (a[j][1] == SENT) |
                           (a[j][2] == SENT) | (a[j][3] == SENT);
                int guard = 0;
                while (__any(miss)) {
                    if (miss) {
#pragma unroll
                        for (int d = 0; d < 4; ++d)
                            a[j][d] = aload(hsrc + j * 16 + d);
                    }
                    miss = (a[j][0] == SENT) | (a[j][1] == SENT) |
                           (a[j][2] == SENT) | (a[j][3] == SENT);
                    if (++guard > (1 << 20)) break;
                }
                union { uint u[4]; short8 s; } cv;
                cv.u[0] = a[j][0]; cv.u[1] = a[j][1];
                cv.u[2] = a[j][2]; cv.u[3] = a[j][3];
                int gB = (j * 4 + q) ^ (brow & 7);
                short8 bf = *(const short8*)((const char*)Ws + brow * 1024 + gB * 16);
                if ((j & 1) == 0)
                    acc0 = __builtin_amdgcn_mfma_f32_16x16x32_bf16(cv.s, bf, acc0, 0, 0, 0);
                else
                    acc1 = __builtin_amdgcn_mfma_f32_16x16x32_bf16(cv.s, bf, acc1, 0, 0, 0);
            }
#pragma unroll
            for (int r = 0; r < 4; ++r)
                gb[w][(q << 2) + r][arow] = acc0[r] + acc1[r];
            __syncthreads();   // the ONLY barrier per step
            gi += gb[0][b][jj];
            gf += gb[1][b][jj];
            gg += gb[2][b][jj];
            go += gb[3][b][jj];
        }
        // cell
        float ii = fsig(gi), ff = fsig(gf), oo = fsig(go), tg = ftanh(gg);
        cst = ff * cst + ii * tg;
        float hv = oo * ftanh(cst);
        // publish pair (one dword per 2 cols) relaxed agent-scope (sc0 sc1)
        uint hbits = (uint)f2bf(hv);
        uint p1 = (uint)__shfl_xor((int)hbits, 1);
        if ((jj & 1) == 0) {
            uint val = hbits | (p1 << 16);
            uint* dst = (uint*)hs + ((long)t * B_ + b) * (H_ / 2) + (g * 16 + jj) / 2;
            __hip_atomic_store(dst, val, __ATOMIC_RELAXED, __HIP_MEMORY_SCOPE_AGENT);
        }
    }
}

// ---------------------------------------------------------------- host ----
extern "C" void kernel_launch(void* const* d_in, const int* in_sizes, int n_in,
                              void* d_out, int out_size, void* d_ws, size_t ws_size,
                              hipStream_t stream) {
    const float* images = (const float*)d_in[0];
    const int* labels   = (const int*)d_in[1];
    const float* embed  = (const float*)d_in[2];
    const float* Wih    = (const float*)d_in[3];
    const float* Whh    = (const float*)d_in[4];
    const float* bih    = (const float*)d_in[5];
    const float* bhh    = (const float*)d_in[6];
    const float* Wfc    = (const float*)d_in[7];
    const float* bfc    = (const float*)d_in[8];
    float* out = (float*)d_out;

    char* p = (char*)d_ws;
    ushort* dWfc = (ushort*)p; p += (long)V_ * H_ * 2;
    ushort* dWih = (ushort*)p; p += (long)GH * D_ * 2;
    ushort* dWhh = (ushort*)p; p += (long)GH * H_ * 2;
    ushort* xseq = (ushort*)p; p += (long)T_ * B_ * D_ * 2;
    float* xg    = (float*)p;  p += (long)T_ * B_ * GH * 4;
    ushort* hs   = (ushort*)p; p += (long)T_ * B_ * H_ * 2;
    float* bsum  = (float*)p;  p += GH * 4;

    // sentinel-fill hs each launch (0xFF bytes = bf16 NaN pairs)
    hipMemsetAsync(hs, 0xFF, (size_t)T_ * B_ * H_ * 2, stream);

    {
        long total = (long)GH * D_ / 4 + (long)GH * H_ / 4 + (long)V_ * H_ / 4 + GH / 4;
        int blocks = (int)((total + 255) / 256);
        prep_convert<<<blocks, 256, 0, stream>>>(Wih, Whh, Wfc, bih, bhh, dWih, dWhh, dWfc, bsum);
    }
    prep_xseq<<<T_ * B_, 64, 0, stream>>>(images, labels, embed, xseq);

    // x_gates: (4096 x 2048) = xseq (4096 x 256) * Wih^T + (b_ih+b_hh)
    gemm_bt<D_><<<dim3(32, 16), 256, 0, stream>>>(xseq, dWih, xg, bsum, GH);

    lstm_scan<<<32, 256, 0, stream>>>(dWhh, xg, hs);

    // logits: (4096 x 32000) = hs (4096 x 512) * Wfc^T + b_fc
    gemm_bt<H_><<<dim3(32, 250), 256, 0, stream>>>(hs, dWfc, out, bfc, V_);
}

// Round 11
// 902.486 us; speedup vs baseline: 3.0639x; 3.0639x over previous
//
#include <hip/hip_runtime.h>

typedef __attribute__((ext_vector_type(8))) short short8;
typedef __attribute__((ext_vector_type(4))) float f32x4;
typedef unsigned int uint;
typedef unsigned short ushort;

#define T_ 256
#define B_ 16
#define D_ 256
#define H_ 512
#define V_ 32000
#define GH 2048   /* 4*H */
#define SENT 0xFFFFFFFFu

__device__ __forceinline__ ushort f2bf(float f) {
    uint u = __float_as_uint(f);
    u += 0x7FFFu + ((u >> 16) & 1u);
    return (ushort)(u >> 16);
}

__device__ __forceinline__ float fsig(float x) {
    return 1.0f / (1.0f + __expf(-x));
}

__device__ __forceinline__ float ftanh(float x) {
    float a = __expf(-2.0f * fabsf(x));
    float t = (1.0f - a) / (1.0f + a);
    return x >= 0.0f ? t : -t;
}

__device__ __forceinline__ void cvt4(const float* s, ushort* d) {
    float4 v = *(const float4*)s;
    ushort4 o;
    o.x = f2bf(v.x); o.y = f2bf(v.y); o.z = f2bf(v.z); o.w = f2bf(v.w);
    *(ushort4*)d = o;
}

__device__ __forceinline__ uint aload(const uint* p) {
    return __hip_atomic_load(p, __ATOMIC_RELAXED, __HIP_MEMORY_SCOPE_AGENT);
}

// ---------------------------------------------------------------- prep ----
__global__ void prep_convert(const float* __restrict__ Wih, const float* __restrict__ Whh,
                             const float* __restrict__ Wfc, const float* __restrict__ bih,
                             const float* __restrict__ bhh,
                             ushort* __restrict__ dWih, ushort* __restrict__ dWhh,
                             ushort* __restrict__ dWfc, float* __restrict__ bsum) {
    const long nA = (long)GH * D_ / 4;
    const long nB = (long)GH * H_ / 4;
    const long nC = (long)V_ * H_ / 4;
    const long nS = GH / 4;
    long i = (long)blockIdx.x * blockDim.x + threadIdx.x;
    if (i >= nA + nB + nC + nS) return;
    if (i < nA) {
        cvt4(Wih + i * 4, dWih + i * 4);
    } else if (i < nA + nB) {
        long j = i - nA;
        cvt4(Whh + j * 4, dWhh + j * 4);
    } else if (i < nA + nB + nC) {
        long j = i - nA - nB;
        cvt4(Wfc + j * 4, dWfc + j * 4);
    } else {
        long j = (i - nA - nB - nC) * 4;
        float4 a = *(const float4*)(bih + j);
        float4 b = *(const float4*)(bhh + j);
        float4 o;
        o.x = a.x + b.x; o.y = a.y + b.y; o.z = a.z + b.z; o.w = a.w + b.w;
        *(float4*)(bsum + j) = o;
    }
}

__global__ void prep_xseq(const float* __restrict__ images, const int* __restrict__ labels,
                          const float* __restrict__ embed, ushort* __restrict__ xseq) {
    int m = blockIdx.x;
    int l = threadIdx.x;
    int t = m >> 4, b = m & 15;
    const float* src = (t == 0) ? (images + b * D_) : (embed + (long)labels[m] * D_);
    cvt4(src + l * 4, xseq + (long)m * D_ + l * 4);
}

// ------------------------------------------------- 128x128 bf16 GEMM ------
// Shared tile body: C(128x128) at (mBase,nBase) = A*B^T + bias.
template <int K>
__device__ __forceinline__ void gemm_tile(const ushort* __restrict__ A,
                                          const ushort* __restrict__ Bw,
                                          float* __restrict__ C,
                                          const float* __restrict__ bias,
                                          int ldc, long mBase, long nBase,
                                          ushort* As, ushort* Bs, int tid) {
    const int lane = tid & 63;
    const int w = tid >> 6;
    const int wr = w >> 1, wc = w & 1;

    f32x4 acc[4][4];
#pragma unroll
    for (int i = 0; i < 4; ++i)
#pragma unroll
        for (int j = 0; j < 4; ++j) acc[i][j] = (f32x4){0.f, 0.f, 0.f, 0.f};

    const char* Ab = (const char*)A;
    const char* Bb = (const char*)Bw;

    for (int kk = 0; kk < K / 64; ++kk) {
#pragma unroll
        for (int it = 0; it < 4; ++it) {
            int c = w * 4 + it;
            int r = c * 8 + (lane >> 3);
            int sg = (lane & 7) ^ (r & 7);
            long aoff = (mBase + r) * (long)(K * 2) + kk * 128 + sg * 16;
            long boff = (nBase + r) * (long)(K * 2) + kk * 128 + sg * 16;
            __builtin_amdgcn_global_load_lds(
                (const __attribute__((address_space(1))) void*)(Ab + aoff),
                (__attribute__((address_space(3))) void*)((char*)As + c * 1024), 16, 0, 0);
            __builtin_amdgcn_global_load_lds(
                (const __attribute__((address_space(1))) void*)(Bb + boff),
                (__attribute__((address_space(3))) void*)((char*)Bs + c * 1024), 16, 0, 0);
        }
        __syncthreads();
#pragma unroll
        for (int k2 = 0; k2 < 2; ++k2) {
            short8 af[4], bfr[4];
#pragma unroll
            for (int mi = 0; mi < 4; ++mi) {
                int mrow = wr * 64 + mi * 16 + (lane & 15);
                int g = (k2 * 4 + (lane >> 4)) ^ (mrow & 7);
                af[mi] = *(const short8*)((const char*)As + mrow * 128 + g * 16);
            }
#pragma unroll
            for (int ni = 0; ni < 4; ++ni) {
                int nrow = wc * 64 + ni * 16 + (lane & 15);
                int g = (k2 * 4 + (lane >> 4)) ^ (nrow & 7);
                bfr[ni] = *(const short8*)((const char*)Bs + nrow * 128 + g * 16);
            }
#pragma unroll
            for (int mi = 0; mi < 4; ++mi)
#pragma unroll
                for (int ni = 0; ni < 4; ++ni)
                    acc[mi][ni] = __builtin_amdgcn_mfma_f32_16x16x32_bf16(
                        af[mi], bfr[ni], acc[mi][ni], 0, 0, 0);
        }
        __syncthreads();
    }
#pragma unroll
    for (int ni = 0; ni < 4; ++ni) {
        long col = nBase + wc * 64 + ni * 16 + (lane & 15);
        float bv = bias[col];
#pragma unroll
        for (int mi = 0; mi < 4; ++mi) {
            long row0 = mBase + wr * 64 + mi * 16 + ((lane >> 4) << 2);
#pragma unroll
            for (int rr = 0; rr < 4; ++rr)
                C[(row0 + rr) * (long)ldc + col] = acc[mi][ni][rr] + bv;
        }
    }
}

template <int K>
__global__ __launch_bounds__(256) void gemm_bt(const ushort* __restrict__ A,
                                               const ushort* __restrict__ Bw,
                                               float* __restrict__ C,
                                               const float* __restrict__ bias,
                                               int ldc) {
    __shared__ ushort As[128 * 64];
    __shared__ ushort Bs[128 * 64];
    gemm_tile<K>(A, Bw, C, bias, ldc,
                 (long)blockIdx.x * 128, (long)blockIdx.y * 128,
                 As, Bs, threadIdx.x);
}

// FC GEMM with XCD-aware tile mapping: xcd = bid&7 owns n-columns n===xcd
// (mod 8); m sweeps contiguously within an XCD -> W_fc panel (131KB) and the
// whole A (hs, 4MB) stay L2-resident per XCD. Cuts B re-fetch ~8x.
__global__ __launch_bounds__(256) void gemm_fc(const ushort* __restrict__ A,
                                               const ushort* __restrict__ Bw,
                                               float* __restrict__ C,
                                               const float* __restrict__ bias) {
    __shared__ ushort As[128 * 64];
    __shared__ ushort Bs[128 * 64];
    int bid = blockIdx.x;
    int xcd = bid & 7;
    int j = bid >> 3;          // 0..1023
    int m = j & 31;            // 0..31
    int n = (j >> 5) * 8 + xcd;   // 0..255
    if (n >= 250) return;
    gemm_tile<H_>(A, Bw, C, bias, V_, (long)m * 128, (long)n * 128,
                  As, Bs, threadIdx.x);
}

// ------------------------------------------------------------- scan ------
// R3 proven structure (578us): 32 blocks; block g owns h cols [g*16,g*16+16).
// Sentinel protocol (hs pre-filled 0xFFFFFFFF = bf16 NaN pair, unreachable for
// h in (-1,1)): producers fire-and-forget relaxed-agent stores; consumers
// spin-reload still-sentinel words; own block's columns come from hloc.
__global__ __launch_bounds__(256) void lstm_scan(const ushort* __restrict__ Whh,
                                                 const float* __restrict__ xg,
                                                 ushort* __restrict__ hs) {
    __shared__ ushort Ws[64 * 512];   // 64 KB
    __shared__ ushort hb[16 * 512];   // 16 KB
    __shared__ float gb[4][16][16];   // 4 KB
    __shared__ ushort hloc[16][16];   // 512 B

    const int tid = threadIdx.x;
    const int lane = tid & 63;
    const int w = tid >> 6;
    const int g = blockIdx.x;

    // load W_hh slice: rows q*16+jj -> global row q*512 + g*16 + jj
#pragma unroll
    for (int j = 0; j < 16; ++j) {
        int gid = j * 256 + tid;
        int row = gid >> 6;
        int gcol = gid & 63;
        int srow = (row >> 4) * H_ + g * 16 + (row & 15);
        uint4 v = *(const uint4*)(Whh + (long)srow * H_ + gcol * 8);
        int dg = gcol ^ (row & 7);
        *(uint4*)((char*)Ws + row * 1024 + dg * 16) = v;
    }
    __syncthreads();

    const int b = tid >> 4;
    const int jj = tid & 15;
    const int row = tid >> 4;
    const int c0 = tid & 15;
    float cst = 0.0f;

    for (int t = 0; t < T_; ++t) {
        long xb = ((long)t * B_ + b) * GH + g * 16 + jj;
        float gi = xg[xb];
        float gf = xg[xb + 512];
        float gg = xg[xb + 1024];
        float go = xg[xb + 1536];

        if (t > 0) {
            // gather h(t-1) row: 16 uints, self-owned words from LDS
            uint vals[16];
#pragma unroll
            for (int j = 0; j < 16; ++j) {
                int u = c0 + j * 16;
                if ((u >> 3) == g)
                    vals[j] = (uint)hloc[row][(u & 7) * 2] |
                              ((uint)hloc[row][(u & 7) * 2 + 1] << 16);
                else
                    vals[j] = SENT;
            }
            uint* hsrcU = (uint*)hs + ((long)(t - 1) * (B_ * H_)) / 2 + row * 256;
            int guard = 0;
            for (;;) {
                int pend = 0;
#pragma unroll
                for (int j = 0; j < 16; ++j) {
                    if (vals[j] == SENT)
                        vals[j] = aload(hsrcU + c0 + j * 16);
                }
#pragma unroll
                for (int j = 0; j < 16; ++j) pend += (vals[j] == SENT) ? 1 : 0;
                if (pend == 0 || ++guard > (1 << 20)) break;
            }
            // scatter into swizzled LDS h-tile
#pragma unroll
            for (int j = 0; j < 16; ++j) {
                int u = c0 + j * 16;
                int gcol = u >> 2, sub = u & 3;
                int dg = gcol ^ (row & 7);
                *(uint*)((char*)hb + row * 1024 + dg * 16 + sub * 4) = vals[j];
            }
            __syncthreads();
            // wave w computes its gate-w 16x16 tile, K=512, 2 accumulators
            f32x4 acc0 = (f32x4){0.f, 0.f, 0.f, 0.f};
            f32x4 acc1 = (f32x4){0.f, 0.f, 0.f, 0.f};
            const int arow = lane & 15;
            const int brow = w * 16 + (lane & 15);
#pragma unroll
            for (int k0 = 0; k0 < 16; k0 += 2) {
                int ga0 = (k0 * 4 + (lane >> 4)) ^ (arow & 7);
                int gB0 = (k0 * 4 + (lane >> 4)) ^ (brow & 7);
                int ga1 = ((k0 + 1) * 4 + (lane >> 4)) ^ (arow & 7);
                int gB1 = ((k0 + 1) * 4 + (lane >> 4)) ^ (brow & 7);
                short8 a0 = *(const short8*)((const char*)hb + arow * 1024 + ga0 * 16);
                short8 b0 = *(const short8*)((const char*)Ws + brow * 1024 + gB0 * 16);
                short8 a1 = *(const short8*)((const char*)hb + arow * 1024 + ga1 * 16);
                short8 b1 = *(const short8*)((const char*)Ws + brow * 1024 + gB1 * 16);
                acc0 = __builtin_amdgcn_mfma_f32_16x16x32_bf16(a0, b0, acc0, 0, 0, 0);
                acc1 = __builtin_amdgcn_mfma_f32_16x16x32_bf16(a1, b1, acc1, 0, 0, 0);
            }
#pragma unroll
            for (int r = 0; r < 4; ++r)
                gb[w][((lane >> 4) << 2) + r][lane & 15] = acc0[r] + acc1[r];
            __syncthreads();
            gi += gb[0][b][jj];
            gf += gb[1][b][jj];
            gg += gb[2][b][jj];
            go += gb[3][b][jj];
        }
        // elementwise LSTM cell; thread owns (b, jj)
        float ii = fsig(gi), ff = fsig(gf), oo = fsig(go), tg = ftanh(gg);
        cst = ff * cst + ii * tg;
        float hv = oo * ftanh(cst);
        ushort hb16 = f2bf(hv);
        hloc[b][jj] = hb16;                       // self-fill source for t+1
        uint mybits = (uint)hb16;
        uint partner = (uint)__shfl_xor((int)mybits, 1);
        if ((jj & 1) == 0) {
            uint val = mybits | (partner << 16);
            uint* dst = (uint*)hs + ((long)t * B_ + b) * (H_ / 2) + (g * 16 + jj) / 2;
            __hip_atomic_store(dst, val, __ATOMIC_RELAXED, __HIP_MEMORY_SCOPE_AGENT);
        }
        __syncthreads();   // hloc visible to all before next step's self-fill
    }
}

// ---------------------------------------------------------------- host ----
extern "C" void kernel_launch(void* const* d_in, const int* in_sizes, int n_in,
                              void* d_out, int out_size, void* d_ws, size_t ws_size,
                              hipStream_t stream) {
    const float* images = (const float*)d_in[0];
    const int* labels   = (const int*)d_in[1];
    const float* embed  = (const float*)d_in[2];
    const float* Wih    = (const float*)d_in[3];
    const float* Whh    = (const float*)d_in[4];
    const float* bih    = (const float*)d_in[5];
    const float* bhh    = (const float*)d_in[6];
    const float* Wfc    = (const float*)d_in[7];
    const float* bfc    = (const float*)d_in[8];
    float* out = (float*)d_out;

    char* p = (char*)d_ws;
    ushort* dWfc = (ushort*)p; p += (long)V_ * H_ * 2;
    ushort* dWih = (ushort*)p; p += (long)GH * D_ * 2;
    ushort* dWhh = (ushort*)p; p += (long)GH * H_ * 2;
    ushort* xseq = (ushort*)p; p += (long)T_ * B_ * D_ * 2;
    float* xg    = (float*)p;  p += (long)T_ * B_ * GH * 4;
    ushort* hs   = (ushort*)p; p += (long)T_ * B_ * H_ * 2;
    float* bsum  = (float*)p;  p += GH * 4;

    // sentinel-fill hs each launch (0xFF bytes = bf16 NaN pairs)
    hipMemsetAsync(hs, 0xFF, (size_t)T_ * B_ * H_ * 2, stream);

    {
        long total = (long)GH * D_ / 4 + (long)GH * H_ / 4 + (long)V_ * H_ / 4 + GH / 4;
        int blocks = (int)((total + 255) / 256);
        prep_convert<<<blocks, 256, 0, stream>>>(Wih, Whh, Wfc, bih, bhh, dWih, dWhh, dWfc, bsum);
    }
    prep_xseq<<<T_ * B_, 64, 0, stream>>>(images, labels, embed, xseq);

    // x_gates: (4096 x 2048) = xseq (4096 x 256) * Wih^T + (b_ih+b_hh)
    gemm_bt<D_><<<dim3(32, 16), 256, 0, stream>>>(xseq, dWih, xg, bsum, GH);

    lstm_scan<<<32, 256, 0, stream>>>(dWhh, xg, hs);

    // logits: (4096 x 32000) = hs * Wfc^T + b_fc, XCD-aware tile mapping
    gemm_fc<<<8192, 256, 0, stream>>>(hs, dWfc, out, bfc);
}